// Round 3
// baseline (2663.313 us; speedup 1.0000x reference)
//
#include <hip/hip_runtime.h>
#include <hip/hip_bf16.h>

typedef _Float16 half8 __attribute__((ext_vector_type(8)));
typedef _Float16 half4 __attribute__((ext_vector_type(4)));
typedef float f32x4 __attribute__((ext_vector_type(4)));

// Geometry: D=256, H=8, A=64, M=400000, N=50000
#define SEGB 16      // segments per block
#define TILE 64      // rows per staged subtile
#define ACCW 520     // padded f32 stride of LDS acc tile (520%32=8 -> lk groups spread banks)

// ---------------- weight transpose + f16 convert ----------------
__global__ void k_convert(const float* __restrict__ Wq, const float* __restrict__ Wk,
                          const float* __restrict__ Wv, const float* __restrict__ Wout,
                          _Float16* __restrict__ wqkT, _Float16* __restrict__ wvT,
                          _Float16* __restrict__ woutT)
{
    int gid = blockIdx.x * 256 + threadIdx.x;
    if (gid < 131072) {
        int h = gid >> 14;
        int d = (gid >> 6) & 255;
        int a = gid & 63;
        wqkT[((h * 64 + a) << 8) + d]       = (_Float16)Wq[gid];
        wqkT[(((8 + h) * 64 + a) << 8) + d] = (_Float16)Wk[gid];
        wvT[((h * 64 + a) << 8) + d]        = (_Float16)Wv[gid];
    } else if (gid < 262144) {
        int g = gid - 131072;
        int k = g >> 8, n = g & 255;
        woutT[(n << 9) + k] = (_Float16)Wout[g];
    }
}

// ---------------- counting sort: hist -> 3-stage scan -> scatter ----------------
__global__ void k_hist(const int* __restrict__ index, int* __restrict__ counts, int M) {
    int m = blockIdx.x * 256 + threadIdx.x;
    if (m < M) atomicAdd(&counts[index[m]], 1);
}

// per-chunk (1024) exclusive scan; chunk totals out
__global__ __launch_bounds__(1024) void k_scan1(const int* __restrict__ counts,
                                                int* __restrict__ starts,
                                                int* __restrict__ blocktot, int N) {
    __shared__ int s[1024];
    int b = blockIdx.x, t = threadIdx.x;
    int i = b * 1024 + t;
    int x = (i < N) ? counts[i] : 0;
    s[t] = x;
    __syncthreads();
    #pragma unroll
    for (int off = 1; off < 1024; off <<= 1) {
        int v = (t >= off) ? s[t - off] : 0;
        __syncthreads();
        s[t] += v;
        __syncthreads();
    }
    if (i < N) starts[i] = s[t] - x;       // chunk-local exclusive
    if (t == 1023) blocktot[b] = s[1023];
}

// serial scan of chunk totals (~49 elements)
__global__ void k_scan2(const int* __restrict__ blocktot, int* __restrict__ blockoff, int NC) {
    if (threadIdx.x == 0 && blockIdx.x == 0) {
        int run = 0;
        for (int i = 0; i < NC; ++i) { blockoff[i] = run; run += blocktot[i]; }
    }
}

// add chunk offsets; produce starts (stable) and cursor (consumed by scatter)
__global__ __launch_bounds__(1024) void k_scan3(int* __restrict__ starts,
                                                int* __restrict__ cursor,
                                                const int* __restrict__ blockoff,
                                                int N, int M) {
    int b = blockIdx.x, t = threadIdx.x;
    int i = b * 1024 + t;
    if (i < N) {
        int v = starts[i] + blockoff[b];
        starts[i] = v;
        cursor[i] = v;
    }
    if (b == 0 && t == 0) starts[N] = M;
}

__global__ void k_scatteridx(const int* __restrict__ index, int* __restrict__ cursor,
                             int* __restrict__ sorted, int M) {
    int m = blockIdx.x * 256 + threadIdx.x;
    if (m < M) {
        int pos = atomicAdd(&cursor[index[m]], 1);
        sorted[pos] = m;
    }
}

// ---------------- fully fused: q,k,e,v, segment-reduce (LDS), out-GEMM ----------------
__global__ __launch_bounds__(256) void k_main(
    const float* __restrict__ msg, const int* __restrict__ index,
    const int* __restrict__ sorted, const int* __restrict__ starts,
    const _Float16* __restrict__ wqkT, const _Float16* __restrict__ wvT,
    const _Float16* __restrict__ woutT, const float* __restrict__ bout,
    float* __restrict__ out, int N)
{
    __shared__ float accs[SEGB * ACCW];   // 33280 B
    __shared__ float sums[SEGB * 8];      // 512 B
    __shared__ int   s_sg[TILE];          // 256 B
    __shared__ _Float16 At[TILE * 256];   // 32768 B; out-tile (16x512 f16) unions into it
    char* lds = (char*)At;

    const int t = threadIdx.x;
    const int g0 = blockIdx.x * SEGB;
    const int rbeg = starts[g0];
    const int rend = starts[g0 + SEGB];

    for (int i = t; i < SEGB * ACCW; i += 256) accs[i] = 0.f;
    if (t < SEGB * 8) sums[t] = 0.f;

    const int w = t >> 6, l = t & 63, lr = l & 15, lk = l >> 4;
    const f32x4 zero = {0.f, 0.f, 0.f, 0.f};
    const float4* msgf4 = (const float4*)msg;

    for (int r0 = rbeg; r0 < rend; r0 += TILE) {
        __syncthreads();  // protects At/s_sg from prev iter readers; also covers zero-init
        if (t < TILE) {
            int row = r0 + t;
            s_sg[t] = (row < rend) ? (index[sorted[row]] - g0) : -1;
        }
        // stage TILE x 256 f32 -> f16 LDS, XOR-swizzled
        #pragma unroll
        for (int it = 0; it < 16; ++it) {
            int e4 = it * 256 + t;
            int row = e4 >> 6;
            int c4 = e4 & 63;
            int gr = r0 + row;
            float4 v = {0.f, 0.f, 0.f, 0.f};
            if (gr < rend) v = msgf4[(long)sorted[gr] * 64 + c4];
            half4 hv = {(_Float16)v.x, (_Float16)v.y, (_Float16)v.z, (_Float16)v.w};
            int b = (row << 9) + (c4 << 3);
            b ^= (row & 7) << 4;
            *(half4*)(lds + b) = hv;
        }
        __syncthreads();

        #pragma unroll
        for (int hi = 0; hi < 2; ++hi) {
            const int h = w * 2 + hi;

            // ---- q,k projections ----
            f32x4 aq[4][4], ak[4][4];
            #pragma unroll
            for (int r = 0; r < 4; ++r) {
                #pragma unroll
                for (int n = 0; n < 4; ++n) { aq[r][n] = zero; ak[r][n] = zero; }
            }
            #pragma unroll
            for (int k0 = 0; k0 < 8; ++k0) {
                half8 a[4];
                #pragma unroll
                for (int r = 0; r < 4; ++r) {
                    int row = r * 16 + lr;
                    int b = (row << 9) + ((k0 * 32 + lk * 8) << 1);
                    b ^= (row & 7) << 4;
                    a[r] = *(const half8*)(lds + b);
                }
                #pragma unroll
                for (int n = 0; n < 4; ++n) {
                    half8 bq = *(const half8*)(wqkT + ((h * 64 + n * 16 + lr) << 8) + k0 * 32 + lk * 8);
                    half8 bk = *(const half8*)(wqkT + (((8 + h) * 64 + n * 16 + lr) << 8) + k0 * 32 + lk * 8);
                    #pragma unroll
                    for (int r = 0; r < 4; ++r) {
                        aq[r][n] = __builtin_amdgcn_mfma_f32_16x16x32_f16(a[r], bq, aq[r][n], 0, 0, 0);
                        ak[r][n] = __builtin_amdgcn_mfma_f32_16x16x32_f16(a[r], bk, ak[r][n], 0, 0, 0);
                    }
                }
            }

            // ---- scores -> e = exp(leaky(s) - 20)  (global shift; ratios unchanged) ----
            float ev[4][4];
            #pragma unroll
            for (int r = 0; r < 4; ++r) {
                float p0 = 0.f, p1 = 0.f, p2 = 0.f, p3 = 0.f;
                #pragma unroll
                for (int n = 0; n < 4; ++n) {
                    p0 += aq[r][n][0] * ak[r][n][0];
                    p1 += aq[r][n][1] * ak[r][n][1];
                    p2 += aq[r][n][2] * ak[r][n][2];
                    p3 += aq[r][n][3] * ak[r][n][3];
                }
                #pragma unroll
                for (int off = 1; off < 16; off <<= 1) {
                    p0 += __shfl_xor(p0, off);
                    p1 += __shfl_xor(p1, off);
                    p2 += __shfl_xor(p2, off);
                    p3 += __shfl_xor(p3, off);
                }
                p0 = (p0 >= 0.f) ? p0 : 0.2f * p0;
                p1 = (p1 >= 0.f) ? p1 : 0.2f * p1;
                p2 = (p2 >= 0.f) ? p2 : 0.2f * p2;
                p3 = (p3 >= 0.f) ? p3 : 0.2f * p3;
                ev[r][0] = __expf(p0 - 20.f);
                ev[r][1] = __expf(p1 - 20.f);
                ev[r][2] = __expf(p2 - 20.f);
                ev[r][3] = __expf(p3 - 20.f);
            }

            // ---- v projection ----
            f32x4 av[4][4];
            #pragma unroll
            for (int r = 0; r < 4; ++r) {
                #pragma unroll
                for (int n = 0; n < 4; ++n) av[r][n] = zero;
            }
            #pragma unroll
            for (int k0 = 0; k0 < 8; ++k0) {
                half8 a[4];
                #pragma unroll
                for (int r = 0; r < 4; ++r) {
                    int row = r * 16 + lr;
                    int b = (row << 9) + ((k0 * 32 + lk * 8) << 1);
                    b ^= (row & 7) << 4;
                    a[r] = *(const half8*)(lds + b);
                }
                #pragma unroll
                for (int n = 0; n < 4; ++n) {
                    half8 bv = *(const half8*)(wvT + ((h * 64 + n * 16 + lr) << 8) + k0 * 32 + lk * 8);
                    #pragma unroll
                    for (int r = 0; r < 4; ++r)
                        av[r][n] = __builtin_amdgcn_mfma_f32_16x16x32_f16(a[r], bv, av[r][n], 0, 0, 0);
                }
            }

            // ---- run-combined flush into LDS acc tile ----
            #pragma unroll
            for (int r = 0; r < 4; ++r) {
                int rb = r * 16 + lk * 4;
                int g0s = s_sg[rb + 0], g1s = s_sg[rb + 1];
                int g2s = s_sg[rb + 2], g3s = s_sg[rb + 3];
                #pragma unroll
                for (int n = 0; n < 4; ++n) {
                    int col = h * 64 + n * 16 + lr;
                    float vsum = av[r][n][0] * ev[r][0];
                    int cur = g0s;
                    if (g1s == cur) vsum += av[r][n][1] * ev[r][1];
                    else {
                        if (cur >= 0) atomicAdd(&accs[cur * ACCW + col], vsum);
                        cur = g1s; vsum = av[r][n][1] * ev[r][1];
                    }
                    if (g2s == cur) vsum += av[r][n][2] * ev[r][2];
                    else {
                        if (cur >= 0) atomicAdd(&accs[cur * ACCW + col], vsum);
                        cur = g2s; vsum = av[r][n][2] * ev[r][2];
                    }
                    if (g3s == cur) vsum += av[r][n][3] * ev[r][3];
                    else {
                        if (cur >= 0) atomicAdd(&accs[cur * ACCW + col], vsum);
                        cur = g3s; vsum = av[r][n][3] * ev[r][3];
                    }
                    if (cur >= 0) atomicAdd(&accs[cur * ACCW + col], vsum);
                }
                if (lr == 0) {
                    float ssum = ev[r][0];
                    int cur = g0s;
                    if (g1s == cur) ssum += ev[r][1];
                    else {
                        if (cur >= 0) atomicAdd(&sums[cur * 8 + h], ssum);
                        cur = g1s; ssum = ev[r][1];
                    }
                    if (g2s == cur) ssum += ev[r][2];
                    else {
                        if (cur >= 0) atomicAdd(&sums[cur * 8 + h], ssum);
                        cur = g2s; ssum = ev[r][2];
                    }
                    if (g3s == cur) ssum += ev[r][3];
                    else {
                        if (cur >= 0) atomicAdd(&sums[cur * 8 + h], ssum);
                        cur = g3s; ssum = ev[r][3];
                    }
                    if (cur >= 0) atomicAdd(&sums[cur * 8 + h], ssum);
                }
            }
        }
    }
    __syncthreads();

    // ---- normalize -> f16 out-tile [16][512] (swizzled, unions into At) ----
    #pragma unroll
    for (int it = 0; it < 8; ++it) {
        int e4 = it * 256 + t;
        int row = e4 >> 7;       // seg 0..15
        int c4 = e4 & 127;       // 4-col group
        int h = c4 >> 4;
        float ss = sums[row * 8 + h];
        float inv = (ss > 0.f) ? 1.f / ss : 0.f;
        f32x4 a = *(const f32x4*)&accs[row * ACCW + c4 * 4];
        half4 hv = {(_Float16)(a[0] * inv), (_Float16)(a[1] * inv),
                    (_Float16)(a[2] * inv), (_Float16)(a[3] * inv)};
        int b = (row << 10) + (c4 << 3);
        b ^= (row & 7) << 4;
        *(half4*)(lds + b) = hv;
    }
    __syncthreads();

    // ---- out-GEMM: [16 segs x 512] @ woutT -> out[16 x 256] ----
    f32x4 ac[4];
    #pragma unroll
    for (int n = 0; n < 4; ++n) ac[n] = zero;
    #pragma unroll
    for (int k0 = 0; k0 < 16; ++k0) {
        int row = lr;
        int b = (row << 10) + ((k0 * 32 + lk * 8) << 1);
        b ^= (row & 7) << 4;
        half8 a = *(const half8*)(lds + b);
        #pragma unroll
        for (int n = 0; n < 4; ++n) {
            half8 bw = *(const half8*)(woutT + ((w * 64 + n * 16 + lr) << 9) + k0 * 32 + lk * 8);
            ac[n] = __builtin_amdgcn_mfma_f32_16x16x32_f16(a, bw, ac[n], 0, 0, 0);
        }
    }
    #pragma unroll
    for (int n = 0; n < 4; ++n) {
        int col = w * 64 + n * 16 + lr;
        float bb = bout[col];
        #pragma unroll
        for (int j = 0; j < 4; ++j) {
            int rowl = lk * 4 + j;
            out[(long)(g0 + rowl) * 256 + col] = ac[n][j] + bb;
        }
    }
}

extern "C" void kernel_launch(void* const* d_in, const int* in_sizes, int n_in,
                              void* d_out, int out_size, void* d_ws, size_t ws_size,
                              hipStream_t stream)
{
    const float* msg   = (const float*)d_in[0];
    const int*   index = (const int*)d_in[1];
    const float* Wq    = (const float*)d_in[4];
    const float* Wk    = (const float*)d_in[5];
    const float* Wv    = (const float*)d_in[6];
    const float* Wout  = (const float*)d_in[7];
    const float* bout  = (const float*)d_in[8];
    float* out = (float*)d_out;

    const int M = in_sizes[0] / 256;   // 400000
    const int N = out_size / 256;      // 50000
    const int NC = (N + 1023) / 1024;  // 49 scan chunks

    char* ws = (char*)d_ws;
    _Float16* wqkT  = (_Float16*)(ws);              // 524288 B
    _Float16* wvT   = (_Float16*)(ws + 524288);     // 262144 B
    _Float16* woutT = (_Float16*)(ws + 786432);     // 262144 B
    int* counts   = (int*)(ws + 1048576);           // N*4
    int* cursor   = (int*)(ws + 1253376);           // N*4
    int* starts   = (int*)(ws + 1458176);           // (N+1)*4
    int* sorted   = (int*)(ws + 1662976);           // M*4
    int* blocktot = (int*)(ws + 3262976);           // NC*4
    int* blockoff = (int*)(ws + 3263232);           // NC*4

    hipMemsetAsync(counts, 0, (size_t)N * 4, stream);

    k_convert<<<1024, 256, 0, stream>>>(Wq, Wk, Wv, Wout, wqkT, wvT, woutT);
    k_hist<<<(M + 255) / 256, 256, 0, stream>>>(index, counts, M);
    k_scan1<<<NC, 1024, 0, stream>>>(counts, starts, blocktot, N);
    k_scan2<<<1, 64, 0, stream>>>(blocktot, blockoff, NC);
    k_scan3<<<NC, 1024, 0, stream>>>(starts, cursor, blockoff, N, M);
    k_scatteridx<<<(M + 255) / 256, 256, 0, stream>>>(index, cursor, sorted, M);
    k_main<<<N / SEGB, 256, 0, stream>>>(msg, index, sorted, starts, wqkT, wvT,
                                         woutT, bout, out, N);
}

// Round 4
// 1376.128 us; speedup vs baseline: 1.9354x; 1.9354x over previous
//
#include <hip/hip_runtime.h>
#include <hip/hip_bf16.h>

typedef _Float16 half8 __attribute__((ext_vector_type(8)));
typedef _Float16 half4 __attribute__((ext_vector_type(4)));
typedef float f32x4 __attribute__((ext_vector_type(4)));

// Geometry: D=256, H=8, A=64, M=400000, N=50000
#define C_SEG 16     // LDS acc capacity (segments); overflow -> global atomic fallback
#define ACCW 516     // padded f32 stride (516*4 bytes, 16B-aligned rows, spreads banks by 4/seg)

// ---------------- weight transpose + f16 convert ----------------
__global__ void k_convert(const float* __restrict__ Wq, const float* __restrict__ Wk,
                          const float* __restrict__ Wv, const float* __restrict__ Wout,
                          _Float16* __restrict__ wqkT, _Float16* __restrict__ wvT,
                          _Float16* __restrict__ woutT)
{
    int gid = blockIdx.x * 256 + threadIdx.x;
    if (gid < 131072) {
        int h = gid >> 14;
        int d = (gid >> 6) & 255;
        int a = gid & 63;
        wqkT[((h * 64 + a) << 8) + d]       = (_Float16)Wq[gid];
        wqkT[(((8 + h) * 64 + a) << 8) + d] = (_Float16)Wk[gid];
        wvT[((h * 64 + a) << 8) + d]        = (_Float16)Wv[gid];
    } else if (gid < 262144) {
        int g = gid - 131072;
        int k = g >> 8, n = g & 255;
        woutT[(n << 9) + k] = (_Float16)Wout[g];
    }
}

// ---------------- counting sort: hist -> 3-stage scan -> scatter ----------------
__global__ void k_hist(const int* __restrict__ index, int* __restrict__ counts, int M) {
    int m = blockIdx.x * 256 + threadIdx.x;
    if (m < M) atomicAdd(&counts[index[m]], 1);
}

__global__ __launch_bounds__(1024) void k_scan1(const int* __restrict__ counts,
                                                int* __restrict__ starts,
                                                int* __restrict__ blocktot, int N) {
    __shared__ int s[1024];
    int b = blockIdx.x, t = threadIdx.x;
    int i = b * 1024 + t;
    int x = (i < N) ? counts[i] : 0;
    s[t] = x;
    __syncthreads();
    #pragma unroll
    for (int off = 1; off < 1024; off <<= 1) {
        int v = (t >= off) ? s[t - off] : 0;
        __syncthreads();
        s[t] += v;
        __syncthreads();
    }
    if (i < N) starts[i] = s[t] - x;
    if (t == 1023) blocktot[b] = s[1023];
}

__global__ void k_scan2(const int* __restrict__ blocktot, int* __restrict__ blockoff, int NC) {
    if (threadIdx.x == 0 && blockIdx.x == 0) {
        int run = 0;
        for (int i = 0; i < NC; ++i) { blockoff[i] = run; run += blocktot[i]; }
    }
}

__global__ __launch_bounds__(1024) void k_scan3(int* __restrict__ starts,
                                                int* __restrict__ cursor,
                                                const int* __restrict__ blockoff,
                                                int N, int M) {
    int b = blockIdx.x, t = threadIdx.x;
    int i = b * 1024 + t;
    if (i < N) {
        int v = starts[i] + blockoff[b];
        starts[i] = v;
        cursor[i] = v;
    }
    if (b == 0 && t == 0) starts[N] = M;
}

__global__ void k_scatteridx(const int* __restrict__ index, int* __restrict__ cursor,
                             int* __restrict__ sorted, int M) {
    int m = blockIdx.x * 256 + threadIdx.x;
    if (m < M) {
        int pos = atomicAdd(&cursor[index[m]], 1);
        sorted[pos] = m;
    }
}

// ---------------- fused: q,k,e,v + LDS segment reduce + boundary-only atomics ----------------
__global__ __launch_bounds__(256) void k_fused2(
    const float* __restrict__ msg, const int* __restrict__ index,
    const int* __restrict__ sorted, const _Float16* __restrict__ wqkT,
    const _Float16* __restrict__ wvT,
    float* __restrict__ segsum, float* __restrict__ acc, int M)
{
    __shared__ _Float16 At[64 * 256];      // 32768 B, XOR-swizzled
    __shared__ float accs[C_SEG * ACCW];   // 33024 B
    __shared__ float sums[C_SEG * 8];      // 512 B
    __shared__ int s_id[64];
    __shared__ int s_sg[64];
    char* lds = (char*)At;
    const int t = threadIdx.x;

    // bijective XCD-chunked swizzle: consecutive sorted chunks stay on one XCD
    int nwg = gridDim.x;
    int qc = nwg >> 3, rc = nwg & 7;
    int xcd = blockIdx.x & 7, off = blockIdx.x >> 3;
    int b = ((xcd < rc) ? xcd * (qc + 1) : rc * (qc + 1) + (xcd - rc) * qc) + off;
    const long m0 = (long)b * 64;

    if (t < 64) {
        long m = m0 + t;
        int sid = (m < M) ? sorted[m] : -1;
        s_id[t] = sid;
        s_sg[t] = (sid >= 0) ? index[sid] : -1;
    }
    for (int i = t; i < C_SEG * ACCW; i += 256) accs[i] = 0.f;
    if (t < C_SEG * 8) sums[t] = 0.f;
    __syncthreads();

    const int lastv = (int)((M - 1 - m0) < 63 ? (M - 1 - m0) : 63);
    const int gl0 = s_sg[0];
    const int ghi = s_sg[lastv];

    // stage gathered 64x256 f32 -> f16 LDS
    const float4* msgf4 = (const float4*)msg;
    #pragma unroll
    for (int it = 0; it < 16; ++it) {
        int e4 = it * 256 + t;
        int row = e4 >> 6;
        int c4 = e4 & 63;
        int sid = s_id[row];
        float4 v = {0.f, 0.f, 0.f, 0.f};
        if (sid >= 0) v = msgf4[(long)sid * 64 + c4];
        half4 hv = {(_Float16)v.x, (_Float16)v.y, (_Float16)v.z, (_Float16)v.w};
        int bb = (row << 9) + (c4 << 3);
        bb ^= (row & 7) << 4;
        *(half4*)(lds + bb) = hv;
    }
    __syncthreads();

    const int w = t >> 6, l = t & 63, lr = l & 15, lk = l >> 4;
    const f32x4 zero = {0.f, 0.f, 0.f, 0.f};

    auto flushv = [&](int cur, float vsum, int col) {
        if (cur >= 0) {
            int ls = cur - gl0;
            if (ls < C_SEG) atomicAdd(&accs[ls * ACCW + col], vsum);
            else atomicAdd(acc + (long)cur * 512 + col, vsum);
        }
    };
    auto flushs = [&](int cur, float ssum, int h) {
        if (cur >= 0) {
            int ls = cur - gl0;
            if (ls < C_SEG) atomicAdd(&sums[ls * 8 + h], ssum);
            else atomicAdd(segsum + (long)cur * 8 + h, ssum);
        }
    };

    #pragma unroll
    for (int hi = 0; hi < 2; ++hi) {
        const int h = w * 2 + hi;

        // ---- q,k projections ----
        f32x4 aq[4][4], ak[4][4];
        #pragma unroll
        for (int r = 0; r < 4; ++r) {
            #pragma unroll
            for (int n = 0; n < 4; ++n) { aq[r][n] = zero; ak[r][n] = zero; }
        }
        #pragma unroll
        for (int k0 = 0; k0 < 8; ++k0) {
            half8 a[4];
            #pragma unroll
            for (int r = 0; r < 4; ++r) {
                int row = r * 16 + lr;
                int bb = (row << 9) + ((k0 * 32 + lk * 8) << 1);
                bb ^= (row & 7) << 4;
                a[r] = *(const half8*)(lds + bb);
            }
            #pragma unroll
            for (int n = 0; n < 4; ++n) {
                half8 bq = *(const half8*)(wqkT + ((h * 64 + n * 16 + lr) << 8) + k0 * 32 + lk * 8);
                half8 bk = *(const half8*)(wqkT + (((8 + h) * 64 + n * 16 + lr) << 8) + k0 * 32 + lk * 8);
                #pragma unroll
                for (int r = 0; r < 4; ++r) {
                    aq[r][n] = __builtin_amdgcn_mfma_f32_16x16x32_f16(a[r], bq, aq[r][n], 0, 0, 0);
                    ak[r][n] = __builtin_amdgcn_mfma_f32_16x16x32_f16(a[r], bk, ak[r][n], 0, 0, 0);
                }
            }
        }

        // ---- scores -> e = exp(leaky(s) - 20) (global shift; ratios unchanged) ----
        float ev[4][4];
        #pragma unroll
        for (int r = 0; r < 4; ++r) {
            float p0 = 0.f, p1 = 0.f, p2 = 0.f, p3 = 0.f;
            #pragma unroll
            for (int n = 0; n < 4; ++n) {
                p0 += aq[r][n][0] * ak[r][n][0];
                p1 += aq[r][n][1] * ak[r][n][1];
                p2 += aq[r][n][2] * ak[r][n][2];
                p3 += aq[r][n][3] * ak[r][n][3];
            }
            #pragma unroll
            for (int off2 = 1; off2 < 16; off2 <<= 1) {
                p0 += __shfl_xor(p0, off2);
                p1 += __shfl_xor(p1, off2);
                p2 += __shfl_xor(p2, off2);
                p3 += __shfl_xor(p3, off2);
            }
            p0 = (p0 >= 0.f) ? p0 : 0.2f * p0;
            p1 = (p1 >= 0.f) ? p1 : 0.2f * p1;
            p2 = (p2 >= 0.f) ? p2 : 0.2f * p2;
            p3 = (p3 >= 0.f) ? p3 : 0.2f * p3;
            ev[r][0] = __expf(p0 - 20.f);
            ev[r][1] = __expf(p1 - 20.f);
            ev[r][2] = __expf(p2 - 20.f);
            ev[r][3] = __expf(p3 - 20.f);
        }

        // ---- v projection ----
        f32x4 av[4][4];
        #pragma unroll
        for (int r = 0; r < 4; ++r) {
            #pragma unroll
            for (int n = 0; n < 4; ++n) av[r][n] = zero;
        }
        #pragma unroll
        for (int k0 = 0; k0 < 8; ++k0) {
            half8 a[4];
            #pragma unroll
            for (int r = 0; r < 4; ++r) {
                int row = r * 16 + lr;
                int bb = (row << 9) + ((k0 * 32 + lk * 8) << 1);
                bb ^= (row & 7) << 4;
                a[r] = *(const half8*)(lds + bb);
            }
            #pragma unroll
            for (int n = 0; n < 4; ++n) {
                half8 bv = *(const half8*)(wvT + ((h * 64 + n * 16 + lr) << 8) + k0 * 32 + lk * 8);
                #pragma unroll
                for (int r = 0; r < 4; ++r)
                    av[r][n] = __builtin_amdgcn_mfma_f32_16x16x32_f16(a[r], bv, av[r][n], 0, 0, 0);
            }
        }

        // ---- run-combined flush into LDS acc tile ----
        #pragma unroll
        for (int r = 0; r < 4; ++r) {
            int rb = r * 16 + lk * 4;
            int g0s = s_sg[rb + 0], g1s = s_sg[rb + 1];
            int g2s = s_sg[rb + 2], g3s = s_sg[rb + 3];
            #pragma unroll
            for (int n = 0; n < 4; ++n) {
                int col = h * 64 + n * 16 + lr;
                float vsum = av[r][n][0] * ev[r][0];
                int cur = g0s;
                if (g1s == cur) vsum += av[r][n][1] * ev[r][1];
                else { flushv(cur, vsum, col); cur = g1s; vsum = av[r][n][1] * ev[r][1]; }
                if (g2s == cur) vsum += av[r][n][2] * ev[r][2];
                else { flushv(cur, vsum, col); cur = g2s; vsum = av[r][n][2] * ev[r][2]; }
                if (g3s == cur) vsum += av[r][n][3] * ev[r][3];
                else { flushv(cur, vsum, col); cur = g3s; vsum = av[r][n][3] * ev[r][3]; }
                flushv(cur, vsum, col);
            }
            if (lr == 0) {
                float ssum = ev[r][0];
                int cur = g0s;
                if (g1s == cur) ssum += ev[r][1];
                else { flushs(cur, ssum, h); cur = g1s; ssum = ev[r][1]; }
                if (g2s == cur) ssum += ev[r][2];
                else { flushs(cur, ssum, h); cur = g2s; ssum = ev[r][2]; }
                if (g3s == cur) ssum += ev[r][3];
                else { flushs(cur, ssum, h); cur = g3s; ssum = ev[r][3]; }
                flushs(cur, ssum, h);
            }
        }
    }
    __syncthreads();

    // ---- epilogue: interior segs -> plain store; boundary segs -> atomicAdd ----
    int nls = ghi - gl0 + 1;
    if (nls > C_SEG) nls = C_SEG;
    for (int ls = 0; ls < nls; ++ls) {
        int g = gl0 + ls;
        bool bdry = (g == gl0) || (g == ghi);
        #pragma unroll
        for (int c = t; c < 512; c += 256) {
            float v = accs[ls * ACCW + c];
            if (bdry) atomicAdd(acc + (long)g * 512 + c, v);
            else acc[(long)g * 512 + c] = v;
        }
    }
    if (t < nls * 8) {
        int ls = t >> 3, h = t & 7;
        int g = gl0 + ls;
        bool bdry = (g == gl0) || (g == ghi);
        float v = sums[ls * 8 + h];
        if (bdry) atomicAdd(segsum + (long)g * 8 + h, v);
        else segsum[(long)g * 8 + h] = v;
    }
}

// ---------------- out = (acc/segsum) @ Wout + bout ----------------
__global__ __launch_bounds__(256) void k_out(
    const float* __restrict__ acc, const float* __restrict__ segsum,
    const _Float16* __restrict__ woutT, const float* __restrict__ bout,
    float* __restrict__ out, int N)
{
    __shared__ _Float16 At[64 * 512];  // 64 KB
    char* lds = (char*)At;
    const int t = threadIdx.x;
    const long n0 = (long)blockIdx.x * 64;

    #pragma unroll
    for (int it = 0; it < 32; ++it) {
        int e4 = it * 256 + t;
        int row = e4 >> 7;
        int c4 = (e4 & 127) << 2;
        long gr = n0 + row;
        float4 v = {0.f, 0.f, 0.f, 0.f};
        float inv = 0.f;
        if (gr < N) {
            v = ((const float4*)acc)[gr * 128 + (e4 & 127)];
            float ss = segsum[gr * 8 + (c4 >> 6)];
            inv = (ss > 0.f) ? 1.f / ss : 0.f;
        }
        half4 hv = {(_Float16)(v.x * inv), (_Float16)(v.y * inv),
                    (_Float16)(v.z * inv), (_Float16)(v.w * inv)};
        int b = (row << 10) + (c4 << 1);
        b ^= (row & 7) << 4;
        *(half4*)(lds + b) = hv;
    }
    __syncthreads();

    const int w = t >> 6, l = t & 63, lr = l & 15, lk = l >> 4;
    const f32x4 zero = {0.f, 0.f, 0.f, 0.f};
    f32x4 ac[4][4];
    #pragma unroll
    for (int r = 0; r < 4; ++r) {
        #pragma unroll
        for (int n = 0; n < 4; ++n) ac[r][n] = zero;
    }
    #pragma unroll
    for (int k0 = 0; k0 < 16; ++k0) {
        half8 a[4];
        #pragma unroll
        for (int r = 0; r < 4; ++r) {
            int row = r * 16 + lr;
            int b = (row << 10) + ((k0 * 32 + lk * 8) << 1);
            b ^= (row & 7) << 4;
            a[r] = *(const half8*)(lds + b);
        }
        #pragma unroll
        for (int n = 0; n < 4; ++n) {
            half8 bw = *(const half8*)(woutT + ((w * 64 + n * 16 + lr) << 9) + k0 * 32 + lk * 8);
            #pragma unroll
            for (int r = 0; r < 4; ++r)
                ac[r][n] = __builtin_amdgcn_mfma_f32_16x16x32_f16(a[r], bw, ac[r][n], 0, 0, 0);
        }
    }
    #pragma unroll
    for (int n = 0; n < 4; ++n) {
        int col = w * 64 + n * 16 + lr;
        float bb = bout[col];
        #pragma unroll
        for (int r = 0; r < 4; ++r) {
            #pragma unroll
            for (int j = 0; j < 4; ++j) {
                long row = n0 + r * 16 + lk * 4 + j;
                if (row < N) out[row * 256 + col] = ac[r][n][j] + bb;
            }
        }
    }
}

extern "C" void kernel_launch(void* const* d_in, const int* in_sizes, int n_in,
                              void* d_out, int out_size, void* d_ws, size_t ws_size,
                              hipStream_t stream)
{
    const float* msg   = (const float*)d_in[0];
    const int*   index = (const int*)d_in[1];
    const float* Wq    = (const float*)d_in[4];
    const float* Wk    = (const float*)d_in[5];
    const float* Wv    = (const float*)d_in[6];
    const float* Wout  = (const float*)d_in[7];
    const float* bout  = (const float*)d_in[8];
    float* out = (float*)d_out;

    const int M = in_sizes[0] / 256;   // 400000
    const int N = out_size / 256;      // 50000
    const int NC = (N + 1023) / 1024;  // 49 scan chunks

    char* ws = (char*)d_ws;
    _Float16* wqkT  = (_Float16*)(ws);              // 524288 B
    _Float16* wvT   = (_Float16*)(ws + 524288);     // 262144 B
    _Float16* woutT = (_Float16*)(ws + 786432);     // 262144 B
    size_t o = 1048576;
    float* segsum = (float*)(ws + o);                                   // N*32 B
    float* acc    = (float*)(ws + o + (size_t)N * 32);                  // N*2048 B
    char*  p2     = ws + o + (size_t)N * 32 + (size_t)N * 2048;
    int* counts   = (int*)(p2);                     // N*4
    int* cursor   = (int*)(p2 + (size_t)N * 4);     // N*4
    int* starts   = (int*)(p2 + (size_t)N * 8);     // (N+1)*4
    int* sorted   = (int*)(p2 + (size_t)N * 12 + 4);// M*4
    int* blocktot = (int*)(p2 + (size_t)N * 12 + 4 + (size_t)M * 4);
    int* blockoff = blocktot + NC;

    // zero segsum + acc + counts (contiguous region)
    hipMemsetAsync(ws + o, 0, (size_t)N * 32 + (size_t)N * 2048 + (size_t)N * 4, stream);

    k_convert<<<1024, 256, 0, stream>>>(Wq, Wk, Wv, Wout, wqkT, wvT, woutT);
    k_hist<<<(M + 255) / 256, 256, 0, stream>>>(index, counts, M);
    k_scan1<<<NC, 1024, 0, stream>>>(counts, starts, blocktot, N);
    k_scan2<<<1, 64, 0, stream>>>(blocktot, blockoff, NC);
    k_scan3<<<NC, 1024, 0, stream>>>(starts, cursor, blockoff, N, M);
    k_scatteridx<<<(M + 255) / 256, 256, 0, stream>>>(index, cursor, sorted, M);
    k_fused2<<<(M + 63) / 64, 256, 0, stream>>>(msg, index, sorted, wqkT, wvT,
                                                segsum, acc, M);
    k_out<<<(N + 63) / 64, 256, 0, stream>>>(acc, segsum, woutT, bout, out, N);
}